// Round 1
// baseline (855.473 us; speedup 1.0000x reference)
//
#include <hip/hip_runtime.h>
#include <math.h>

#define BB 8
#define SS 4096
#define HH 1024
#define EE 256
#define KK 64
#define HQ 256
#define NEGF -1e30f

// Generic per-row MLP score: out[r] = tanh(X[r,:] @ W1 + b1) @ w2 + b2
// X: [nrows, HH], W1: [HH, HQ=256], w2: [256], 256 threads, TOK rows per WG.
template<int TOK>
__global__ __launch_bounds__(256) void mlp_score_kernel(
    const float* __restrict__ X, const float* __restrict__ w1,
    const float* __restrict__ b1, const float* __restrict__ w2,
    const float* __restrict__ b2, float* __restrict__ out)
{
    __shared__ float xs[TOK][64];
    __shared__ float red[4][TOK];
    const int tid = threadIdx.x;                 // column j in [0,256)
    const long row0 = (long)blockIdx.x * TOK;
    float acc[TOK];
#pragma unroll
    for (int t = 0; t < TOK; t++) acc[t] = 0.f;
    const float* xb = X + row0 * HH;

    for (int k0 = 0; k0 < HH; k0 += 64) {
        __syncthreads();
        for (int i = tid; i < TOK * 64; i += 256) {
            int t = i >> 6, kk = i & 63;
            xs[t][kk] = xb[(long)t * HH + k0 + kk];
        }
        __syncthreads();
#pragma unroll 4
        for (int kk = 0; kk < 64; kk++) {
            float w = w1[(long)(k0 + kk) * HQ + tid];   // coalesced across tid
#pragma unroll
            for (int t = 0; t < TOK; t++) acc[t] = fmaf(xs[t][kk], w, acc[t]);
        }
    }
    const float bb1 = b1[tid], ww2 = w2[tid];
    const int lane = tid & 63, wv = tid >> 6;
#pragma unroll
    for (int t = 0; t < TOK; t++) {
        float v = tanhf(acc[t] + bb1) * ww2;
#pragma unroll
        for (int off = 32; off > 0; off >>= 1) v += __shfl_down(v, off, 64);
        if (lane == 0) red[wv][t] = v;
    }
    __syncthreads();
    if (tid < TOK)
        out[row0 + tid] = red[0][tid] + red[1][tid] + red[2][tid] + red[3][tid] + b2[0];
}

// Per (b,k): masked max and sum(exp(s-max)) over the contiguous token range.
__global__ __launch_bounds__(256) void block_stats_kernel(
    const float* __restrict__ scores, const int* __restrict__ mask,
    const int* __restrict__ bnd, float* __restrict__ bmax, float* __restrict__ bden)
{
    const int b = blockIdx.x >> 6, k = blockIdx.x & 63;
    const int start = bnd[b * KK + k];
    const int end = (k == KK - 1) ? SS : bnd[b * KK + k + 1];
    const int tid = threadIdx.x;
    __shared__ float r[4];
    __shared__ float mshared;

    float m = NEGF;
    for (int s = start + tid; s < end; s += 256)
        if (mask[b * SS + s] == 1) m = fmaxf(m, scores[b * SS + s]);
    for (int off = 32; off > 0; off >>= 1) m = fmaxf(m, __shfl_down(m, off, 64));
    if ((tid & 63) == 0) r[tid >> 6] = m;
    __syncthreads();
    if (tid == 0) mshared = fmaxf(fmaxf(r[0], r[1]), fmaxf(r[2], r[3]));
    __syncthreads();
    m = mshared;

    float d = 0.f;
    for (int s = start + tid; s < end; s += 256)
        if (mask[b * SS + s] == 1) d += expf(scores[b * SS + s] - m);
    for (int off = 32; off > 0; off >>= 1) d += __shfl_down(d, off, 64);
    __syncthreads();
    if ((tid & 63) == 0) r[tid >> 6] = d;
    __syncthreads();
    if (tid == 0) { bmax[blockIdx.x] = m; bden[blockIdx.x] = r[0] + r[1] + r[2] + r[3]; }
}

// Per (b,k): embed[b,k,:] = sum_{s in range, masked} softmax-weight(s) * hidden[b,s,:]
__global__ __launch_bounds__(256) void block_embed_kernel(
    const float* __restrict__ hidden, const float* __restrict__ scores,
    const int* __restrict__ mask, const int* __restrict__ bnd,
    const float* __restrict__ bmax, const float* __restrict__ bden,
    float* __restrict__ embed)
{
    const int b = blockIdx.x >> 6, k = blockIdx.x & 63;
    const int start = bnd[b * KK + k];
    const int end = (k == KK - 1) ? SS : bnd[b * KK + k + 1];
    const int tid = threadIdx.x;
    const float m = bmax[blockIdx.x];
    const float den = bden[blockIdx.x];
    const float inv = (den > 0.f) ? 1.f / fmaxf(den, 1e-30f) : 0.f;

    float a0 = 0.f, a1 = 0.f, a2 = 0.f, a3 = 0.f;
    for (int s = start; s < end; s++) {
        if (mask[b * SS + s] != 1) continue;
        const float w = expf(scores[b * SS + s] - m) * inv;
        const float* hr = hidden + ((long)b * SS + s) * HH;
        a0 = fmaf(w, hr[tid], a0);
        a1 = fmaf(w, hr[tid + 256], a1);
        a2 = fmaf(w, hr[tid + 512], a2);
        a3 = fmaf(w, hr[tid + 768], a3);
    }
    float* er = embed + (long)blockIdx.x * HH;
    er[tid] = a0; er[tid + 256] = a1; er[tid + 512] = a2; er[tid + 768] = a3;
}

// Per batch: block softmax (validity via denom>0), func = sum_k bw*embed,
// out = func @ out_w + out_b, then L2-normalize.
__global__ __launch_bounds__(256) void finalize_kernel(
    const float* __restrict__ embed, const float* __restrict__ bscores,
    const float* __restrict__ bden, const float* __restrict__ out_w,
    const float* __restrict__ out_b, float* __restrict__ outp)
{
    const int b = blockIdx.x, tid = threadIdx.x;
    __shared__ float bw[KK];
    __shared__ float func[HH];
    __shared__ float r[4];

    if (tid < KK) {   // exactly wave 0
        float s = (bden[b * KK + tid] > 0.f) ? bscores[b * KK + tid] : NEGF;
        float m = s;
        for (int off = 32; off > 0; off >>= 1) m = fmaxf(m, __shfl_xor(m, off, 64));
        float e = expf(s - m);
        float d = e;
        for (int off = 32; off > 0; off >>= 1) d += __shfl_xor(d, off, 64);
        bw[tid] = e / d;
    }
    __syncthreads();

    for (int h = tid; h < HH; h += 256) {
        float f = 0.f;
        for (int k = 0; k < KK; k++)
            f = fmaf(bw[k], embed[((long)b * KK + k) * HH + h], f);
        func[h] = f;
    }
    __syncthreads();

    float o = 0.f;
    for (int h = 0; h < HH; h++)
        o = fmaf(func[h], out_w[(long)h * EE + tid], o);
    o += out_b[tid];

    float sq = o * o;
    for (int off = 32; off > 0; off >>= 1) sq += __shfl_down(sq, off, 64);
    if ((tid & 63) == 0) r[tid >> 6] = sq;
    __syncthreads();
    const float nrm = sqrtf(r[0] + r[1] + r[2] + r[3]);
    outp[b * EE + tid] = o / fmaxf(nrm, 1e-12f);
}

extern "C" void kernel_launch(void* const* d_in, const int* in_sizes, int n_in,
                              void* d_out, int out_size, void* d_ws, size_t ws_size,
                              hipStream_t stream) {
    const float* hidden  = (const float*)d_in[0];
    const int*   mask    = (const int*)  d_in[1];
    const int*   bnd     = (const int*)  d_in[2];
    const float* tok_w1  = (const float*)d_in[3];
    const float* tok_b1  = (const float*)d_in[4];
    const float* tok_w2  = (const float*)d_in[5];
    const float* tok_b2  = (const float*)d_in[6];
    const float* blk_w1  = (const float*)d_in[7];
    const float* blk_b1  = (const float*)d_in[8];
    const float* blk_w2  = (const float*)d_in[9];
    const float* blk_b2  = (const float*)d_in[10];
    const float* out_w   = (const float*)d_in[11];
    const float* out_b   = (const float*)d_in[12];

    float* ws      = (float*)d_ws;
    float* scores  = ws;                          // [B*S]   = 32768
    float* bmax    = ws + 32768;                  // [B*K]   = 512
    float* bden    = ws + 33280;                  // [B*K]   = 512
    float* embed   = ws + 33792;                  // [B*K*H] = 524288
    float* bscores = ws + 33792 + BB * KK * HH;   // [B*K]   = 512

    mlp_score_kernel<16><<<BB * SS / 16, 256, 0, stream>>>(
        hidden, tok_w1, tok_b1, tok_w2, tok_b2, scores);
    block_stats_kernel<<<BB * KK, 256, 0, stream>>>(scores, mask, bnd, bmax, bden);
    block_embed_kernel<<<BB * KK, 256, 0, stream>>>(
        hidden, scores, mask, bnd, bmax, bden, embed);
    mlp_score_kernel<4><<<BB * KK / 4, 256, 0, stream>>>(
        embed, blk_w1, blk_b1, blk_w2, blk_b2, bscores);
    finalize_kernel<<<BB, 256, 0, stream>>>(
        embed, bscores, bden, out_w, out_b, (float*)d_out);
}

// Round 2
// 474.361 us; speedup vs baseline: 1.8034x; 1.8034x over previous
//
#include <hip/hip_runtime.h>
#include <math.h>

#define BB 8
#define SS 4096
#define HH 1024
#define EE 256
#define KK 64
#define HQ 256
#define NEGF -1e30f

typedef short bf16x8 __attribute__((ext_vector_type(8)));
typedef float f32x4  __attribute__((ext_vector_type(4)));

__device__ inline short f2bf(float x) {
    unsigned u = __float_as_uint(x);
    unsigned r = (u + 0x7fffu + ((u >> 16) & 1u)) >> 16;   // RNE
    return (short)r;
}

// w1s[kb][n][kk] = bf16(w1[(kb*32+kk)*HQ + n]); kb in [0,32), n in [0,256), kk in [0,32)
__global__ __launch_bounds__(256) void convert_w1_kernel(
    const float* __restrict__ w1, short* __restrict__ w1s)
{
    const int kb = blockIdx.x, n = threadIdx.x;
    for (int kk = 0; kk < 32; kk++)
        w1s[kb * 8192 + n * 32 + kk] = f2bf(w1[(kb * 32 + kk) * HQ + n]);
}

// Token scores via bf16 MFMA: 64 rows/WG x 256 cols, fused tanh*w2 reduction.
// Wave w owns cols [64w, 64w+64): 4 row-tiles x 4 col-tiles of 16x16x32.
__global__ __launch_bounds__(256) void mfma_score_kernel(
    const float* __restrict__ X, const short* __restrict__ w1s,
    const float* __restrict__ b1, const float* __restrict__ w2,
    const float* __restrict__ b2, float* __restrict__ out)
{
    __shared__ __attribute__((aligned(16))) short xs[64 * 40];    // X tile [row][k], pad 40
    __shared__ __attribute__((aligned(16))) short wsx[256 * 40];  // W1^T tile [n][k], pad 40
    __shared__ float part[4][64];

    const int t = threadIdx.x;
    const int wv = t >> 6, lane = t & 63, lo = lane & 15, q = lane >> 4;
    const long row0 = (long)blockIdx.x * 64;

    // staging assignment for X: thread t -> row t>>2, k-group (t&3)*8
    const int srow = t >> 2, skg = (t & 3) * 8;
    const float* xrow = X + (row0 + srow) * HH;

    f32x4 acc[4][4];
#pragma unroll
    for (int i = 0; i < 4; i++)
#pragma unroll
        for (int j = 0; j < 4; j++) acc[i][j] = (f32x4){0.f, 0.f, 0.f, 0.f};

    for (int kb = 0; kb < 32; kb++) {
        __syncthreads();
        {   // stage X (f32 -> bf16): 64 rows x 32 k
            const float4* p = (const float4*)(xrow + kb * 32 + skg);
            float4 v0 = p[0], v1 = p[1];
            bf16x8 pk;
            pk[0] = f2bf(v0.x); pk[1] = f2bf(v0.y); pk[2] = f2bf(v0.z); pk[3] = f2bf(v0.w);
            pk[4] = f2bf(v1.x); pk[5] = f2bf(v1.y); pk[6] = f2bf(v1.z); pk[7] = f2bf(v1.w);
            *(bf16x8*)(xs + srow * 40 + skg) = pk;
            // stage W1 tile: thread t covers n=t, all 32 k (64B contiguous global)
            const uint4* src = (const uint4*)(w1s + kb * 8192 + t * 32);
            uint4 a0 = src[0], a1 = src[1], a2 = src[2], a3 = src[3];
            uint4* dst = (uint4*)(wsx + t * 40);
            dst[0] = a0; dst[1] = a1; dst[2] = a2; dst[3] = a3;
        }
        __syncthreads();

        bf16x8 af[4], bfr[4];
#pragma unroll
        for (int rt = 0; rt < 4; rt++)
            af[rt] = *(bf16x8*)(xs + (rt * 16 + lo) * 40 + q * 8);
#pragma unroll
        for (int ct = 0; ct < 4; ct++)
            bfr[ct] = *(bf16x8*)(wsx + (wv * 64 + ct * 16 + lo) * 40 + q * 8);
#pragma unroll
        for (int rt = 0; rt < 4; rt++)
#pragma unroll
            for (int ct = 0; ct < 4; ct++)
                acc[rt][ct] = __builtin_amdgcn_mfma_f32_16x16x32_bf16(
                    af[rt], bfr[ct], acc[rt][ct], 0, 0, 0);
    }

    // epilogue: rowpart[rt][reg] = sum_c tanh(acc + b1[c]) * w2[c]
    float rowpart[4][4];
#pragma unroll
    for (int rt = 0; rt < 4; rt++)
#pragma unroll
        for (int r = 0; r < 4; r++) rowpart[rt][r] = 0.f;
#pragma unroll
    for (int ct = 0; ct < 4; ct++) {
        const int c = wv * 64 + ct * 16 + lo;
        const float b1c = b1[c], w2c = w2[c];
#pragma unroll
        for (int rt = 0; rt < 4; rt++)
#pragma unroll
            for (int r = 0; r < 4; r++)
                rowpart[rt][r] += tanhf(acc[rt][ct][r] + b1c) * w2c;
    }
#pragma unroll
    for (int rt = 0; rt < 4; rt++)
#pragma unroll
        for (int r = 0; r < 4; r++) {
            float v = rowpart[rt][r];
            v += __shfl_down(v, 8, 64);
            v += __shfl_down(v, 4, 64);
            v += __shfl_down(v, 2, 64);
            v += __shfl_down(v, 1, 64);
            rowpart[rt][r] = v;   // valid on lanes with lo==0
        }
    if (lo == 0)
#pragma unroll
        for (int rt = 0; rt < 4; rt++)
#pragma unroll
            for (int r = 0; r < 4; r++)
                part[wv][rt * 16 + q * 4 + r] = rowpart[rt][r];
    __syncthreads();
    if (t < 64)
        out[row0 + t] = part[0][t] + part[1][t] + part[2][t] + part[3][t] + b2[0];
}

// Per (b,k): masked max + denom over contiguous range; write normalized token
// weights wtok (0 for masked/invalid/empty).
__global__ __launch_bounds__(256) void block_stats_kernel(
    const float* __restrict__ scores, const int* __restrict__ mask,
    const int* __restrict__ bnd, float* __restrict__ bmax, float* __restrict__ bden,
    float* __restrict__ wtok)
{
    const int b = blockIdx.x >> 6, k = blockIdx.x & 63;
    const int start = bnd[b * KK + k];
    const int end = (k == KK - 1) ? SS : bnd[b * KK + k + 1];
    const int tid = threadIdx.x;
    __shared__ float r[4];
    __shared__ float mshared, dshared;

    float m = NEGF;
    for (int s = start + tid; s < end; s += 256)
        if (mask[b * SS + s] == 1) m = fmaxf(m, scores[b * SS + s]);
    for (int off = 32; off > 0; off >>= 1) m = fmaxf(m, __shfl_down(m, off, 64));
    if ((tid & 63) == 0) r[tid >> 6] = m;
    __syncthreads();
    if (tid == 0) mshared = fmaxf(fmaxf(r[0], r[1]), fmaxf(r[2], r[3]));
    __syncthreads();
    m = mshared;

    float d = 0.f;
    for (int s = start + tid; s < end; s += 256)
        if (mask[b * SS + s] == 1) d += expf(scores[b * SS + s] - m);
    for (int off = 32; off > 0; off >>= 1) d += __shfl_down(d, off, 64);
    __syncthreads();
    if ((tid & 63) == 0) r[tid >> 6] = d;
    __syncthreads();
    if (tid == 0) {
        float den = r[0] + r[1] + r[2] + r[3];
        bmax[blockIdx.x] = m; bden[blockIdx.x] = den;
        dshared = (den > 0.f) ? 1.f / fmaxf(den, 1e-30f) : 0.f;
    }
    __syncthreads();
    const float inv = dshared;
    for (int s = start + tid; s < end; s += 256)
        wtok[b * SS + s] = (mask[b * SS + s] == 1) ? expf(scores[b * SS + s] - m) * inv : 0.f;
}

// Parallel weighted accumulation: grid = B x (S/32) chunks; 256 threads, each
// owns h, h+256, h+512, h+768. atomicAdd into embed at block transitions.
#define TCH 32
__global__ __launch_bounds__(256) void block_embed2_kernel(
    const float* __restrict__ hidden, const float* __restrict__ wtok,
    const int* __restrict__ bnd, float* __restrict__ embed)
{
    const int b = blockIdx.x >> 7;          // 4096/32 = 128 chunks per batch
    const int ch = blockIdx.x & 127;
    const int t = threadIdx.x;
    __shared__ int bsh[KK];
    if (t < KK) bsh[t] = bnd[b * KK + t];
    __syncthreads();

    const int s0 = ch * TCH, s1 = s0 + TCH;
    int cur = -1;
    for (int i = 0; i < KK; i++) if (bsh[i] <= s0) cur = i;   // uniform scan

    float a0 = 0.f, a1 = 0.f, a2 = 0.f, a3 = 0.f;
    bool any = false;
    for (int s = s0; s < s1; s++) {
        while (cur + 1 < KK && bsh[cur + 1] <= s) {
            if (any) {
                float* e = embed + ((long)b * KK + cur) * HH;
                atomicAdd(e + t, a0); atomicAdd(e + t + 256, a1);
                atomicAdd(e + t + 512, a2); atomicAdd(e + t + 768, a3);
                a0 = a1 = a2 = a3 = 0.f; any = false;
            }
            cur++;
        }
        if (cur < 0) continue;
        const float w = wtok[b * SS + s];
        if (w != 0.f) {
            const float* hr = hidden + ((long)b * SS + s) * HH;
            a0 = fmaf(w, hr[t], a0);
            a1 = fmaf(w, hr[t + 256], a1);
            a2 = fmaf(w, hr[t + 512], a2);
            a3 = fmaf(w, hr[t + 768], a3);
            any = true;
        }
    }
    if (any) {
        float* e = embed + ((long)b * KK + cur) * HH;
        atomicAdd(e + t, a0); atomicAdd(e + t + 256, a1);
        atomicAdd(e + t + 512, a2); atomicAdd(e + t + 768, a3);
    }
}

// Small f32 MLP score (for the 512 block rows)
template<int TOK>
__global__ __launch_bounds__(256) void mlp_score_kernel(
    const float* __restrict__ X, const float* __restrict__ w1,
    const float* __restrict__ b1, const float* __restrict__ w2,
    const float* __restrict__ b2, float* __restrict__ out)
{
    __shared__ float xs[TOK][64];
    __shared__ float red[4][TOK];
    const int tid = threadIdx.x;
    const long row0 = (long)blockIdx.x * TOK;
    float acc[TOK];
#pragma unroll
    for (int t = 0; t < TOK; t++) acc[t] = 0.f;
    const float* xb = X + row0 * HH;

    for (int k0 = 0; k0 < HH; k0 += 64) {
        __syncthreads();
        for (int i = tid; i < TOK * 64; i += 256) {
            int t = i >> 6, kk = i & 63;
            xs[t][kk] = xb[(long)t * HH + k0 + kk];
        }
        __syncthreads();
#pragma unroll 4
        for (int kk = 0; kk < 64; kk++) {
            float w = w1[(long)(k0 + kk) * HQ + tid];
#pragma unroll
            for (int t = 0; t < TOK; t++) acc[t] = fmaf(xs[t][kk], w, acc[t]);
        }
    }
    const float bb1 = b1[tid], ww2 = w2[tid];
    const int lane = tid & 63, wv = tid >> 6;
#pragma unroll
    for (int t = 0; t < TOK; t++) {
        float v = tanhf(acc[t] + bb1) * ww2;
#pragma unroll
        for (int off = 32; off > 0; off >>= 1) v += __shfl_down(v, off, 64);
        if (lane == 0) red[wv][t] = v;
    }
    __syncthreads();
    if (tid < TOK)
        out[row0 + tid] = red[0][tid] + red[1][tid] + red[2][tid] + red[3][tid] + b2[0];
}

__global__ __launch_bounds__(256) void finalize_kernel(
    const float* __restrict__ embed, const float* __restrict__ bscores,
    const float* __restrict__ bden, const float* __restrict__ out_w,
    const float* __restrict__ out_b, float* __restrict__ outp)
{
    const int b = blockIdx.x, tid = threadIdx.x;
    __shared__ float bw[KK];
    __shared__ float func[HH];
    __shared__ float r[4];

    if (tid < KK) {
        float s = (bden[b * KK + tid] > 0.f) ? bscores[b * KK + tid] : NEGF;
        float m = s;
        for (int off = 32; off > 0; off >>= 1) m = fmaxf(m, __shfl_xor(m, off, 64));
        float e = expf(s - m);
        float d = e;
        for (int off = 32; off > 0; off >>= 1) d += __shfl_xor(d, off, 64);
        bw[tid] = e / d;
    }
    __syncthreads();

    for (int h = tid; h < HH; h += 256) {
        float f = 0.f;
        for (int k = 0; k < KK; k++)
            f = fmaf(bw[k], embed[((long)b * KK + k) * HH + h], f);
        func[h] = f;
    }
    __syncthreads();

    float o = 0.f;
    for (int h = 0; h < HH; h++)
        o = fmaf(func[h], out_w[(long)h * EE + tid], o);
    o += out_b[0 + tid];

    float sq = o * o;
    for (int off = 32; off > 0; off >>= 1) sq += __shfl_down(sq, off, 64);
    if ((tid & 63) == 0) r[tid >> 6] = sq;
    __syncthreads();
    const float nrm = sqrtf(r[0] + r[1] + r[2] + r[3]);
    outp[b * EE + tid] = o / fmaxf(nrm, 1e-12f);
}

extern "C" void kernel_launch(void* const* d_in, const int* in_sizes, int n_in,
                              void* d_out, int out_size, void* d_ws, size_t ws_size,
                              hipStream_t stream) {
    const float* hidden  = (const float*)d_in[0];
    const int*   mask    = (const int*)  d_in[1];
    const int*   bnd     = (const int*)  d_in[2];
    const float* tok_w1  = (const float*)d_in[3];
    const float* tok_b1  = (const float*)d_in[4];
    const float* tok_w2  = (const float*)d_in[5];
    const float* tok_b2  = (const float*)d_in[6];
    const float* blk_w1  = (const float*)d_in[7];
    const float* blk_b1  = (const float*)d_in[8];
    const float* blk_w2  = (const float*)d_in[9];
    const float* blk_b2  = (const float*)d_in[10];
    const float* out_w   = (const float*)d_in[11];
    const float* out_b   = (const float*)d_in[12];

    float* ws      = (float*)d_ws;
    float* wtok    = ws;                         // [B*S]   = 32768
    float* embed   = ws + 32768;                 // [B*K*H] = 524288
    float* scores  = ws + 557056;                // [B*S]   = 32768
    float* bmax    = ws + 589824;                // [B*K]
    float* bden    = ws + 590336;                // [B*K]
    float* bscores = ws + 590848;                // [B*K]
    short* w1s     = (short*)(ws + 591360);      // [32*256*32] bf16

    // zero wtok+embed (contiguous)
    hipMemsetAsync(d_ws, 0, (size_t)557056 * 4, stream);

    convert_w1_kernel<<<32, 256, 0, stream>>>(tok_w1, w1s);
    mfma_score_kernel<<<BB * SS / 64, 256, 0, stream>>>(
        hidden, w1s, tok_b1, tok_w2, tok_b2, scores);
    block_stats_kernel<<<BB * KK, 256, 0, stream>>>(scores, mask, bnd, bmax, bden, wtok);
    block_embed2_kernel<<<BB * SS / TCH, 256, 0, stream>>>(hidden, wtok, bnd, embed);
    mlp_score_kernel<4><<<BB * KK / 4, 256, 0, stream>>>(
        embed, blk_w1, blk_b1, blk_w2, blk_b2, bscores);
    finalize_kernel<<<BB, 256, 0, stream>>>(
        embed, bscores, bden, out_w, out_b, (float*)d_out);
}

// Round 3
// 328.294 us; speedup vs baseline: 2.6058x; 1.4449x over previous
//
#include <hip/hip_runtime.h>
#include <math.h>

#define BB 8
#define SS 4096
#define HH 1024
#define EE 256
#define KK 64
#define HQ 256
#define NEGF -1e30f

typedef short bf16x8 __attribute__((ext_vector_type(8)));
typedef float f32x4  __attribute__((ext_vector_type(4)));

__device__ inline short f2bf(float x) {
    unsigned u = __float_as_uint(x);
    unsigned r = (u + 0x7fffu + ((u >> 16) & 1u)) >> 16;   // RNE
    return (short)r;
}

// w1s[kb][n][kk] = bf16(w1[(kb*32+kk)*HQ + n]); kb in [0,32), n in [0,256), kk in [0,32)
__global__ __launch_bounds__(256) void convert_w1_kernel(
    const float* __restrict__ w1, short* __restrict__ w1s)
{
    const int kb = blockIdx.x, n = threadIdx.x;
    for (int kk = 0; kk < 32; kk++)
        w1s[kb * 8192 + n * 32 + kk] = f2bf(w1[(kb * 32 + kk) * HQ + n]);
}

// Row scores via bf16 MFMA: 64 rows/WG x 256 cols, fused tanh*w2 reduction.
// Wave w owns cols [64w, 64w+64): 4 row-tiles x 4 col-tiles of 16x16x32.
__global__ __launch_bounds__(256) void mfma_score_kernel(
    const float* __restrict__ X, const short* __restrict__ w1s,
    const float* __restrict__ b1, const float* __restrict__ w2,
    const float* __restrict__ b2, float* __restrict__ out)
{
    __shared__ __attribute__((aligned(16))) short xs[64 * 40];    // X tile [row][k], pad 40
    __shared__ __attribute__((aligned(16))) short wsx[256 * 40];  // W1^T tile [n][k], pad 40
    __shared__ float part[4][64];

    const int t = threadIdx.x;
    const int wv = t >> 6, lane = t & 63, lo = lane & 15, q = lane >> 4;
    const long row0 = (long)blockIdx.x * 64;

    const int srow = t >> 2, skg = (t & 3) * 8;
    const float* xrow = X + (row0 + srow) * HH;

    f32x4 acc[4][4];
#pragma unroll
    for (int i = 0; i < 4; i++)
#pragma unroll
        for (int j = 0; j < 4; j++) acc[i][j] = (f32x4){0.f, 0.f, 0.f, 0.f};

    for (int kb = 0; kb < 32; kb++) {
        __syncthreads();
        {
            const float4* p = (const float4*)(xrow + kb * 32 + skg);
            float4 v0 = p[0], v1 = p[1];
            bf16x8 pk;
            pk[0] = f2bf(v0.x); pk[1] = f2bf(v0.y); pk[2] = f2bf(v0.z); pk[3] = f2bf(v0.w);
            pk[4] = f2bf(v1.x); pk[5] = f2bf(v1.y); pk[6] = f2bf(v1.z); pk[7] = f2bf(v1.w);
            *(bf16x8*)(xs + srow * 40 + skg) = pk;
            const uint4* src = (const uint4*)(w1s + kb * 8192 + t * 32);
            uint4 a0 = src[0], a1 = src[1], a2 = src[2], a3 = src[3];
            uint4* dst = (uint4*)(wsx + t * 40);
            dst[0] = a0; dst[1] = a1; dst[2] = a2; dst[3] = a3;
        }
        __syncthreads();

        bf16x8 af[4], bfr[4];
#pragma unroll
        for (int rt = 0; rt < 4; rt++)
            af[rt] = *(bf16x8*)(xs + (rt * 16 + lo) * 40 + q * 8);
#pragma unroll
        for (int ct = 0; ct < 4; ct++)
            bfr[ct] = *(bf16x8*)(wsx + (wv * 64 + ct * 16 + lo) * 40 + q * 8);
#pragma unroll
        for (int rt = 0; rt < 4; rt++)
#pragma unroll
            for (int ct = 0; ct < 4; ct++)
                acc[rt][ct] = __builtin_amdgcn_mfma_f32_16x16x32_bf16(
                    af[rt], bfr[ct], acc[rt][ct], 0, 0, 0);
    }

    float rowpart[4][4];
#pragma unroll
    for (int rt = 0; rt < 4; rt++)
#pragma unroll
        for (int r = 0; r < 4; r++) rowpart[rt][r] = 0.f;
#pragma unroll
    for (int ct = 0; ct < 4; ct++) {
        const int c = wv * 64 + ct * 16 + lo;
        const float b1c = b1[c], w2c = w2[c];
#pragma unroll
        for (int rt = 0; rt < 4; rt++)
#pragma unroll
            for (int r = 0; r < 4; r++)
                rowpart[rt][r] += tanhf(acc[rt][ct][r] + b1c) * w2c;
    }
#pragma unroll
    for (int rt = 0; rt < 4; rt++)
#pragma unroll
        for (int r = 0; r < 4; r++) {
            float v = rowpart[rt][r];
            v += __shfl_down(v, 8, 64);
            v += __shfl_down(v, 4, 64);
            v += __shfl_down(v, 2, 64);
            v += __shfl_down(v, 1, 64);
            rowpart[rt][r] = v;
        }
    if (lo == 0)
#pragma unroll
        for (int rt = 0; rt < 4; rt++)
#pragma unroll
            for (int r = 0; r < 4; r++)
                part[wv][rt * 16 + q * 4 + r] = rowpart[rt][r];
    __syncthreads();
    if (t < 64)
        out[row0 + t] = part[0][t] + part[1][t] + part[2][t] + part[3][t] + b2[0];
}

// Per (b,k): masked max + denom over contiguous range; write normalized token
// weights wtok (0 for masked/invalid/empty).
__global__ __launch_bounds__(256) void block_stats_kernel(
    const float* __restrict__ scores, const int* __restrict__ mask,
    const int* __restrict__ bnd, float* __restrict__ bmax, float* __restrict__ bden,
    float* __restrict__ wtok)
{
    const int b = blockIdx.x >> 6, k = blockIdx.x & 63;
    const int start = bnd[b * KK + k];
    const int end = (k == KK - 1) ? SS : bnd[b * KK + k + 1];
    const int tid = threadIdx.x;
    __shared__ float r[4];
    __shared__ float mshared, dshared;

    float m = NEGF;
    for (int s = start + tid; s < end; s += 256)
        if (mask[b * SS + s] == 1) m = fmaxf(m, scores[b * SS + s]);
    for (int off = 32; off > 0; off >>= 1) m = fmaxf(m, __shfl_down(m, off, 64));
    if ((tid & 63) == 0) r[tid >> 6] = m;
    __syncthreads();
    if (tid == 0) mshared = fmaxf(fmaxf(r[0], r[1]), fmaxf(r[2], r[3]));
    __syncthreads();
    m = mshared;

    float d = 0.f;
    for (int s = start + tid; s < end; s += 256)
        if (mask[b * SS + s] == 1) d += expf(scores[b * SS + s] - m);
    for (int off = 32; off > 0; off >>= 1) d += __shfl_down(d, off, 64);
    __syncthreads();
    if ((tid & 63) == 0) r[tid >> 6] = d;
    __syncthreads();
    if (tid == 0) {
        float den = r[0] + r[1] + r[2] + r[3];
        bmax[blockIdx.x] = m; bden[blockIdx.x] = den;
        dshared = (den > 0.f) ? 1.f / fmaxf(den, 1e-30f) : 0.f;
    }
    __syncthreads();
    const float inv = dshared;
    for (int s = start + tid; s < end; s += 256)
        wtok[b * SS + s] = (mask[b * SS + s] == 1) ? expf(scores[b * SS + s] - m) * inv : 0.f;
}

// Parallel weighted accumulation: grid = B x (S/32) chunks; 256 threads, each
// owns h, h+256, h+512, h+768. atomicAdd into embed at block transitions.
#define TCH 32
__global__ __launch_bounds__(256) void block_embed2_kernel(
    const float* __restrict__ hidden, const float* __restrict__ wtok,
    const int* __restrict__ bnd, float* __restrict__ embed)
{
    const int b = blockIdx.x >> 7;
    const int ch = blockIdx.x & 127;
    const int t = threadIdx.x;
    __shared__ int bsh[KK];
    if (t < KK) bsh[t] = bnd[b * KK + t];
    __syncthreads();

    const int s0 = ch * TCH, s1 = s0 + TCH;
    int cur = -1;
    for (int i = 0; i < KK; i++) if (bsh[i] <= s0) cur = i;

    float a0 = 0.f, a1 = 0.f, a2 = 0.f, a3 = 0.f;
    bool any = false;
    for (int s = s0; s < s1; s++) {
        while (cur + 1 < KK && bsh[cur + 1] <= s) {
            if (any) {
                float* e = embed + ((long)b * KK + cur) * HH;
                atomicAdd(e + t, a0); atomicAdd(e + t + 256, a1);
                atomicAdd(e + t + 512, a2); atomicAdd(e + t + 768, a3);
                a0 = a1 = a2 = a3 = 0.f; any = false;
            }
            cur++;
        }
        if (cur < 0) continue;
        const float w = wtok[b * SS + s];
        if (w != 0.f) {
            const float* hr = hidden + ((long)b * SS + s) * HH;
            a0 = fmaf(w, hr[t], a0);
            a1 = fmaf(w, hr[t + 256], a1);
            a2 = fmaf(w, hr[t + 512], a2);
            a3 = fmaf(w, hr[t + 768], a3);
            any = true;
        }
    }
    if (any) {
        float* e = embed + ((long)b * KK + cur) * HH;
        atomicAdd(e + t, a0); atomicAdd(e + t + 256, a1);
        atomicAdd(e + t + 512, a2); atomicAdd(e + t + 768, a3);
    }
}

// Per batch (1024 threads): block softmax -> func -> out GEMV (H split 4-way)
// -> L2 normalize.
__global__ __launch_bounds__(1024) void finalize_kernel(
    const float* __restrict__ embed, const float* __restrict__ bscores,
    const float* __restrict__ bden, const float* __restrict__ out_w,
    const float* __restrict__ out_b, float* __restrict__ outp)
{
    const int b = blockIdx.x, tid = threadIdx.x;
    __shared__ float bw[KK];
    __shared__ float func[HH];
    __shared__ float red[4][EE];
    __shared__ float osh[EE];
    __shared__ float r4[4];

    if (tid < KK) {   // wave 0
        float s = (bden[b * KK + tid] > 0.f) ? bscores[b * KK + tid] : NEGF;
        float m = s;
        for (int off = 32; off > 0; off >>= 1) m = fmaxf(m, __shfl_xor(m, off, 64));
        float e = expf(s - m);
        float d = e;
        for (int off = 32; off > 0; off >>= 1) d += __shfl_xor(d, off, 64);
        bw[tid] = e / d;
    }
    __syncthreads();

    {   // func[h]: one thread per h
        float f = 0.f;
        const float* ep = embed + (long)b * KK * HH + tid;
#pragma unroll
        for (int k = 0; k < KK; k++)
            f = fmaf(bw[k], ep[(long)k * HH], f);
        func[tid] = f;
    }
    __syncthreads();

    {   // out GEMV: thread (hc, e) accumulates h in [hc*256, hc*256+256)
        const int e = tid & 255, hc = tid >> 8;
        float o = 0.f;
        const float* wp = out_w + (long)hc * 256 * EE + e;
#pragma unroll 8
        for (int h = 0; h < 256; h++)
            o = fmaf(func[hc * 256 + h], wp[(long)h * EE], o);
        red[hc][e] = o;
    }
    __syncthreads();

    if (tid < 256) {
        float oo = red[0][tid] + red[1][tid] + red[2][tid] + red[3][tid] + out_b[tid];
        osh[tid] = oo;
        float sq = oo * oo;
        for (int off = 32; off > 0; off >>= 1) sq += __shfl_down(sq, off, 64);
        if ((tid & 63) == 0) r4[tid >> 6] = sq;
    }
    __syncthreads();
    if (tid < 256) {
        const float nrm = sqrtf(r4[0] + r4[1] + r4[2] + r4[3]);
        outp[b * EE + tid] = osh[tid] / fmaxf(nrm, 1e-12f);
    }
}

extern "C" void kernel_launch(void* const* d_in, const int* in_sizes, int n_in,
                              void* d_out, int out_size, void* d_ws, size_t ws_size,
                              hipStream_t stream) {
    const float* hidden  = (const float*)d_in[0];
    const int*   mask    = (const int*)  d_in[1];
    const int*   bnd     = (const int*)  d_in[2];
    const float* tok_w1  = (const float*)d_in[3];
    const float* tok_b1  = (const float*)d_in[4];
    const float* tok_w2  = (const float*)d_in[5];
    const float* tok_b2  = (const float*)d_in[6];
    const float* blk_w1  = (const float*)d_in[7];
    const float* blk_b1  = (const float*)d_in[8];
    const float* blk_w2  = (const float*)d_in[9];
    const float* blk_b2  = (const float*)d_in[10];
    const float* out_w   = (const float*)d_in[11];
    const float* out_b   = (const float*)d_in[12];

    float* ws      = (float*)d_ws;
    float* wtok    = ws;                         // [B*S]   = 32768
    float* embed   = ws + 32768;                 // [B*K*H] = 524288
    float* scores  = ws + 557056;                // [B*S]   = 32768
    float* bmax    = ws + 589824;                // [B*K]
    float* bden    = ws + 590336;                // [B*K]
    float* bscores = ws + 590848;                // [B*K]
    short* w1s     = (short*)(ws + 591360);      // [32*256*32] bf16 (reused tok->blk)

    hipMemsetAsync(d_ws, 0, (size_t)557056 * 4, stream);   // zero wtok+embed

    convert_w1_kernel<<<32, 256, 0, stream>>>(tok_w1, w1s);
    mfma_score_kernel<<<BB * SS / 64, 256, 0, stream>>>(
        hidden, w1s, tok_b1, tok_w2, tok_b2, scores);
    block_stats_kernel<<<BB * KK, 256, 0, stream>>>(scores, mask, bnd, bmax, bden, wtok);
    block_embed2_kernel<<<BB * SS / TCH, 256, 0, stream>>>(hidden, wtok, bnd, embed);
    // block-score path: reuse w1s buffer (stream-ordered after token GEMM)
    convert_w1_kernel<<<32, 256, 0, stream>>>(blk_w1, w1s);
    mfma_score_kernel<<<BB * KK / 64, 256, 0, stream>>>(
        embed, w1s, blk_b1, blk_w2, blk_b2, bscores);
    finalize_kernel<<<BB, 1024, 0, stream>>>(
        embed, bscores, bden, out_w, out_b, (float*)d_out);
}